// Round 2
// baseline (497.886 us; speedup 1.0000x reference)
//
#include <hip/hip_runtime.h>
#include <hip/hip_bf16.h>

typedef unsigned short u16;
typedef __attribute__((ext_vector_type(8))) short short8;
typedef __attribute__((ext_vector_type(4))) float f32x4;

#define N_AGENTS 131072
#define HID 128
#define FUT 12
#define OBS 8

constexpr int M_TILE = 16;   // agents per tile
constexpr int AG     = 4;    // tiles processed per block

__device__ __forceinline__ u16 f2bf(float f) {
    union { float f; unsigned int i; } v; v.f = f;
    unsigned int u = v.i;
    return (u16)((u + 0x7fffu + ((u >> 16) & 1u)) >> 16);
}
__device__ __forceinline__ float fast_exp2(float x) {
#if __has_builtin(__builtin_amdgcn_exp2f)
    return __builtin_amdgcn_exp2f(x);
#else
    return exp2f(x);
#endif
}
__device__ __forceinline__ float fast_rcp(float x) {
#if __has_builtin(__builtin_amdgcn_rcpf)
    return __builtin_amdgcn_rcpf(x);
#else
    return 1.0f / x;
#endif
}
__device__ __forceinline__ float sigm(float x) {
    return fast_rcp(1.0f + fast_exp2(-1.4426950408889634f * x));
}
__device__ __forceinline__ float tanh_(float x) {
    return 2.0f * fast_rcp(1.0f + fast_exp2(-2.8853900817779268f * x)) - 1.0f;
}

__launch_bounds__(256, 2)
__global__ void lstm_dec_kernel(const float* __restrict__ obs,
                                const float* __restrict__ h0g,
                                const float* __restrict__ Wih,
                                const float* __restrict__ Whh,
                                const float* __restrict__ bih,
                                const float* __restrict__ bhh,
                                const float* __restrict__ Wout,
                                const float* __restrict__ bout,
                                float* __restrict__ dout)
{
    // h tile double-buffered (bf16): rows padded to 17*short8 = 136 u16 = 272B
    __shared__ short8 hb[2][M_TILE][17];
    __shared__ float  xt[M_TILE][2];

    const int tid  = threadIdx.x;
    const int lane = tid & 63;
    const int wv   = tid >> 6;      // wave 0..3, owns hidden [32*wv, 32*wv+32)
    const int r    = lane & 15;     // row (A) / col (B/D) index within 16-tile
    const int kb   = lane >> 4;     // k-block of 8 elems; also D row-block

    const float bout0 = bout[0];
    const float bout1 = bout[1];

    // per-lane gate-column constants: nt 0..7 -> gate type (nt>>1), sub (nt&1)
    int   cols[8];
    float wih0[8], wih1[8], beff[8];
#pragma unroll
    for (int nt = 0; nt < 8; ++nt) {
        int c = (nt >> 1) * 128 + wv * 32 + (nt & 1) * 16 + r;
        cols[nt] = c;
        wih0[nt] = Wih[c * 2 + 0];
        wih1[nt] = Wih[c * 2 + 1];
        beff[nt] = bih[c] + bhh[c] + wih0[nt] * bout0 + wih1[nt] * bout1;
    }

    // build W_eff = W_hh + W_ih @ W_out b-fragments (bf16) in registers
    short8 bfrag[8][4];
    short8 outb[4];
#pragma unroll
    for (int kf = 0; kf < 4; ++kf) {
        const int k0 = kf * 32 + kb * 8;
        float wo0[8], wo1[8];
        short8 ob;
#pragma unroll
        for (int j = 0; j < 8; ++j) {
            wo0[j] = Wout[0 * HID + k0 + j];
            wo1[j] = Wout[1 * HID + k0 + j];
            float sel = (r == 0) ? wo0[j] : ((r == 1) ? wo1[j] : 0.0f);
            ob[j] = (short)f2bf(sel);
        }
        outb[kf] = ob;
#pragma unroll
        for (int nt = 0; nt < 8; ++nt) {
            short8 t;
#pragma unroll
            for (int j = 0; j < 8; ++j) {
                float f = Whh[cols[nt] * HID + k0 + j]
                        + wih0[nt] * wo0[j] + wih1[nt] * wo1[j];
                t[j] = (short)f2bf(f);
            }
            bfrag[nt][kf] = t;
        }
    }

    for (int t = 0; t < AG; ++t) {
        const int A0 = (blockIdx.x * AG + t) * M_TILE;

        f32x4 cfr[2];
#pragma unroll
        for (int sub = 0; sub < 2; ++sub) cfr[sub] = f32x4{0.f, 0.f, 0.f, 0.f};

        short8 afrag[4];
        for (int s = 0; s <= FUT; ++s) {
            // ---- A fragments: h(s-1), row = r (agent), k = kf*32 + kb*8 ----
            if (s == 0) {
#pragma unroll
                for (int kf = 0; kf < 4; ++kf) {
                    const float* hp = h0g + (size_t)(A0 + r) * HID + kf * 32 + kb * 8;
                    f32x4 lo = *(const f32x4*)(hp);
                    f32x4 hi = *(const f32x4*)(hp + 4);
                    short8 a;
#pragma unroll
                    for (int j = 0; j < 4; ++j) { a[j] = (short)f2bf(lo[j]); a[4 + j] = (short)f2bf(hi[j]); }
                    afrag[kf] = a;
                }
            } else {
                const int rb = (s - 1) & 1;
#pragma unroll
                for (int kf = 0; kf < 4; ++kf)
                    afrag[kf] = hb[rb][r][kf * 4 + kb];
            }

            // ---- gate GEMM ----
            f32x4 acc[8];
            if (s < FUT) {
#pragma unroll
                for (int nt = 0; nt < 8; ++nt) acc[nt] = f32x4{0.f, 0.f, 0.f, 0.f};
#pragma unroll
                for (int kf = 0; kf < 4; ++kf) {
#pragma unroll
                    for (int nt = 0; nt < 8; ++nt)
                        acc[nt] = __builtin_amdgcn_mfma_f32_16x16x32_bf16(
                            afrag[kf], bfrag[nt][kf], acc[nt], 0, 0, 0);
                }
            }

            // ---- out tile (wave 0): h(s-1) @ W_out^T ----
            if (wv == 0) {
                f32x4 oacc = {0.f, 0.f, 0.f, 0.f};
#pragma unroll
                for (int kf = 0; kf < 4; ++kf)
                    oacc = __builtin_amdgcn_mfma_f32_16x16x32_bf16(
                        afrag[kf], outb[kf], oacc, 0, 0, 0);
                if (s == 0) {
                    if (r < 2) {
#pragma unroll
                        for (int q = 0; q < 4; ++q)
                            xt[kb * 4 + q][r] = oacc[q] + (r == 0 ? bout0 : bout1);
                    }
                } else {
                    if (r < 2) {
                        const float bo = (r == 0) ? bout0 : bout1;
#pragma unroll
                        for (int q = 0; q < 4; ++q) {
                            int ag = A0 + kb * 4 + q;
                            dout[(size_t)((s - 1) * N_AGENTS + ag) * 2 + r] = oacc[q] + bo;
                        }
                    }
                }
            }

            // ---- step-0 exact correction: gates += (x0 - x~0) @ W_ih^T ----
            if (s == 0) {
                __syncthreads();  // x~0 visible
#pragma unroll
                for (int q = 0; q < 4; ++q) {
                    int a  = kb * 4 + q;
                    int ag = A0 + a;
                    float dx0 = obs[(size_t)((OBS - 1) * N_AGENTS + ag) * 2 + 0] - xt[a][0];
                    float dx1 = obs[(size_t)((OBS - 1) * N_AGENTS + ag) * 2 + 1] - xt[a][1];
#pragma unroll
                    for (int nt = 0; nt < 8; ++nt)
                        acc[nt][q] += dx0 * wih0[nt] + dx1 * wih1[nt];
                }
            }

            // ---- activations + c/h update, write h(s) to LDS (bf16) ----
            if (s < FUT) {
                const int wb = s & 1;
                u16* hbase = (u16*)&hb[wb][0][0];
#pragma unroll
                for (int sub = 0; sub < 2; ++sub) {
#pragma unroll
                    for (int q = 0; q < 4; ++q) {
                        float iv = sigm (acc[0 + sub][q] + beff[0 + sub]);
                        float fv = sigm (acc[2 + sub][q] + beff[2 + sub]);
                        float gv = tanh_(acc[4 + sub][q] + beff[4 + sub]);
                        float ov = sigm (acc[6 + sub][q] + beff[6 + sub]);
                        float cn = fv * cfr[sub][q] + iv * gv;
                        cfr[sub][q] = cn;
                        float hv = ov * tanh_(cn);
                        int row = kb * 4 + q;                 // agent
                        int col = wv * 32 + sub * 16 + r;     // hidden idx
                        hbase[row * 136 + col] = f2bf(hv);
                    }
                }
            }
            __syncthreads();
        }
    }
}

extern "C" void kernel_launch(void* const* d_in, const int* in_sizes, int n_in,
                              void* d_out, int out_size, void* d_ws, size_t ws_size,
                              hipStream_t stream) {
    const float* obs  = (const float*)d_in[0];
    // d_in[1] (fut_traj_rel) is unused by the reference
    const float* h0   = (const float*)d_in[2];
    const float* Wih  = (const float*)d_in[3];
    const float* Whh  = (const float*)d_in[4];
    const float* bih  = (const float*)d_in[5];
    const float* bhh  = (const float*)d_in[6];
    const float* Wout = (const float*)d_in[7];
    const float* bo   = (const float*)d_in[8];
    float* out = (float*)d_out;

    dim3 grid(N_AGENTS / (M_TILE * AG));   // 2048 blocks
    lstm_dec_kernel<<<grid, 256, 0, stream>>>(obs, h0, Wih, Whh, bih, bhh, Wout, bo, out);
}